// Round 1
// 274.850 us; speedup vs baseline: 1.0168x; 1.0168x over previous
//
#include <hip/hip_runtime.h>
#include <hip/hip_fp16.h>

#define NU 100000
#define NI 50000
#define NE 1000000
#define D  64
#define NBI 196            // item buckets of 256
#define NBU 391            // user buckets of 256
#define NB_TOT (NBI + NBU)
#define CHUNK 4096         // edges per k_part_both block (16 per thread)

// fp16 storage: values here are O(10) max (unit-normal emb, means + self*sw),
// so fp16 (2^-11 rel err) strictly beats the previously-shipped bf16 (2^-9).
__device__ __forceinline__ unsigned short f2h(float f) {
    return __half_as_ushort(__float2half(f));   // v_cvt_f16_f32, RNE
}
__device__ __forceinline__ float h2f(unsigned short h) {
    return __half2float(__ushort_as_half(h));
}

// ---- bucket histograms for both partitions + fused f32->fp16 input conversion ----
__global__ void k_bhist_cvt(const int* __restrict__ esrc, const int* __restrict__ edst,
                            int* __restrict__ bcnt,
                            const float* __restrict__ ue, const float* __restrict__ ie,
                            unsigned short* __restrict__ u0h, unsigned short* __restrict__ i0h) {
    __shared__ int h[NB_TOT];
    for (int b = threadIdx.x; b < NB_TOT; b += blockDim.x) h[b] = 0;
    __syncthreads();
    int gt = blockIdx.x * blockDim.x + threadIdx.x;
    int gs = gridDim.x * blockDim.x;
    for (int e = gt; e < NE; e += gs) {
        atomicAdd(&h[edst[e] >> 8], 1);
        atomicAdd(&h[NBI + (esrc[e] >> 8)], 1);
    }
    // fused conversion (streaming BW work hides under the atomic-latency hist phase)
    const float4* uf = (const float4*)ue;
    ushort4* uh = (ushort4*)u0h;
    for (int i = gt; i < NU * (D / 4); i += gs) {
        float4 v = uf[i];
        ushort4 o; o.x = f2h(v.x); o.y = f2h(v.y); o.z = f2h(v.z); o.w = f2h(v.w);
        uh[i] = o;
    }
    const float4* if4 = (const float4*)ie;
    ushort4* ih = (ushort4*)i0h;
    for (int i = gt; i < NI * (D / 4); i += gs) {
        float4 v = if4[i];
        ushort4 o; o.x = f2h(v.x); o.y = f2h(v.y); o.z = f2h(v.z); o.w = f2h(v.w);
        ih[i] = o;
    }
    __syncthreads();
    for (int b = threadIdx.x; b < NB_TOT; b += blockDim.x) {
        int v = h[b];
        if (v) atomicAdd(&bcnt[b], v);
    }
}

// ---- both exclusive scans in one dispatch: block 0 = items, block 1 = users ----
__global__ void k_bscan_both(const int* __restrict__ bcnt,
                             int* __restrict__ bbase_i, int* __restrict__ gcur_i,
                             int* __restrict__ bbase_u, int* __restrict__ gcur_u) {
    __shared__ int s[512];
    int tid = threadIdx.x;
    const int* in = (blockIdx.x == 0) ? bcnt : bcnt + NBI;
    int nb        = (blockIdx.x == 0) ? NBI : NBU;
    int* bbase    = (blockIdx.x == 0) ? bbase_i : bbase_u;
    int* gcur     = (blockIdx.x == 0) ? gcur_i : gcur_u;
    int v = (tid < nb) ? in[tid] : 0;
    s[tid] = v;
    __syncthreads();
    for (int o = 1; o < 512; o <<= 1) {
        int t = (tid >= o) ? s[tid - o] : 0;
        __syncthreads();
        s[tid] += t;
        __syncthreads();
    }
    if (tid < nb) { int ex = s[tid] - v; bbase[tid] = ex; gcur[tid] = ex; }
    if (tid == 0) bbase[nb] = NE;
}

// ---- partition BOTH sides' packed records in one pass over the edge list ----
__global__ void k_part_both(const int* __restrict__ esrc, const int* __restrict__ edst,
                            int* __restrict__ gcur_i, int* __restrict__ gcur_u,
                            unsigned int* __restrict__ rec_i, unsigned int* __restrict__ rec_u) {
    __shared__ int cnt_i[NBI], gb_i[NBI], cnt_u[NBU], gb_u[NBU];
    int tid = threadIdx.x;
    for (int b = tid; b < NBI; b += 256) cnt_i[b] = 0;
    for (int b = tid; b < NBU; b += 256) cnt_u[b] = 0;
    __syncthreads();
    int base = blockIdx.x * CHUNK;
    int dd[16], uu[16], ki[16], ku[16];
#pragma unroll
    for (int k = 0; k < 16; k++) {
        int j = base + tid + k * 256;
        dd[k] = -1;
        if (j < NE) {
            dd[k] = edst[j]; uu[k] = esrc[j];
            ki[k] = atomicAdd(&cnt_i[dd[k] >> 8], 1);
            ku[k] = atomicAdd(&cnt_u[uu[k] >> 8], 1);
        }
    }
    __syncthreads();
    for (int b = tid; b < NBI; b += 256) { int v = cnt_i[b]; if (v) gb_i[b] = atomicAdd(&gcur_i[b], v); }
    for (int b = tid; b < NBU; b += 256) { int v = cnt_u[b]; if (v) gb_u[b] = atomicAdd(&gcur_u[b], v); }
    __syncthreads();
#pragma unroll
    for (int k = 0; k < 16; k++) {
        if (dd[k] >= 0) {
            rec_i[gb_i[dd[k] >> 8] + ki[k]] = ((unsigned int)(dd[k] & 255) << 17) | (unsigned int)uu[k];
            rec_u[gb_u[uu[k] >> 8] + ku[k]] = ((unsigned int)(uu[k] & 255) << 17) | (unsigned int)dd[k];
        }
    }
}

// ---- per-bucket local fill, both sides: one block per bucket task ----
__global__ void k_local_both(const unsigned int* __restrict__ rec_i, const unsigned int* __restrict__ rec_u,
                             const int* __restrict__ bbase_i, const int* __restrict__ bbase_u,
                             int* __restrict__ rp_i, int* __restrict__ rp_u,
                             int* __restrict__ col_i, int* __restrict__ col_u) {
    __shared__ int cnt[256];
    __shared__ int off[256];
    int tid = threadIdx.x;
    int t = blockIdx.x;
    bool item = t < NBI;
    int b = item ? t : t - NBI;
    const unsigned int* rec = item ? rec_i : rec_u;
    const int* bb = item ? bbase_i : bbase_u;
    int* rp  = item ? rp_i : rp_u;
    int* col = item ? col_i : col_u;
    int nn   = item ? NI : NU;
    int beg = bb[b], end = bb[b + 1];
    cnt[tid] = 0;
    __syncthreads();
    for (int j = beg + tid; j < end; j += 256)
        atomicAdd(&cnt[rec[j] >> 17], 1);
    __syncthreads();
    int v = cnt[tid];
    off[tid] = v;
    __syncthreads();
    for (int o = 1; o < 256; o <<= 1) {
        int tv = (tid >= o) ? off[tid - o] : 0;
        __syncthreads();
        off[tid] += tv;
        __syncthreads();
    }
    int ex = off[tid] - v;
    int node = b * 256 + tid;
    if (node <= nn) rp[node] = beg + ex;
    cnt[tid] = ex;
    __syncthreads();
    for (int j = beg + tid; j < end; j += 256) {
        unsigned int r = rec[j];
        int p = atomicAdd(&cnt[r >> 17], 1);
        col[beg + p] = (int)(r & 0x1FFFF);
    }
}

// ---- agg, 16 lanes per node (4 nodes/wave), fp16 gathers everywhere ----
// li = lane&15 owns dims [li*4, li*4+4) as ushort4 (8 B); lb = lane&48 = shfl group base.
// WF: write f32 final output; WH: write fp16 shadow.
// NOTE: selfh/outh may alias (r1 user side updates u0h -> u1h in place) -> no __restrict__.
template<bool WF, bool WH>
__device__ __forceinline__ void agg_h(const unsigned short* __restrict__ feat,
        const unsigned short* selfh, const float* __restrict__ sw,
        const int* __restrict__ rp, const int* __restrict__ cols,
        float* __restrict__ outf, unsigned short* outh,
        int n, int li, int lb) {
    int beg = rp[n], end = rp[n + 1];
    float ax = 0.f, ay = 0.f, az = 0.f, aw = 0.f;
    for (int j0 = beg; j0 < end; j0 += 16) {
        int cv = (j0 + li < end) ? cols[j0 + li] : 0;   // one load covers 16 edges
        int nj = end - j0; if (nj > 16) nj = 16;
        int j = 0;
        for (; j + 4 <= nj; j += 4) {
            int c0 = __shfl(cv, lb + j,     64);
            int c1 = __shfl(cv, lb + j + 1, 64);
            int c2 = __shfl(cv, lb + j + 2, 64);
            int c3 = __shfl(cv, lb + j + 3, 64);
            ushort4 h0 = *(const ushort4*)(feat + (size_t)c0 * D + li * 4);
            ushort4 h1 = *(const ushort4*)(feat + (size_t)c1 * D + li * 4);
            ushort4 h2 = *(const ushort4*)(feat + (size_t)c2 * D + li * 4);
            ushort4 h3 = *(const ushort4*)(feat + (size_t)c3 * D + li * 4);
            ax += h2f(h0.x) + h2f(h1.x) + h2f(h2.x) + h2f(h3.x);
            ay += h2f(h0.y) + h2f(h1.y) + h2f(h2.y) + h2f(h3.y);
            az += h2f(h0.z) + h2f(h1.z) + h2f(h2.z) + h2f(h3.z);
            aw += h2f(h0.w) + h2f(h1.w) + h2f(h2.w) + h2f(h3.w);
        }
        for (; j < nj; ++j) {
            int c = __shfl(cv, lb + j, 64);
            ushort4 h = *(const ushort4*)(feat + (size_t)c * D + li * 4);
            ax += h2f(h.x); ay += h2f(h.y); az += h2f(h.z); aw += h2f(h.w);
        }
    }
    int dgr = end - beg;
    float inv = (dgr > 0) ? (1.0f / (float)dgr) : 0.0f;
    float swv = sw[n];
    ushort4 s4 = *(const ushort4*)(selfh + (size_t)n * D + li * 4);
    float rx = ax * inv + h2f(s4.x) * swv;
    float ry = ay * inv + h2f(s4.y) * swv;
    float rz = az * inv + h2f(s4.z) * swv;
    float rw = aw * inv + h2f(s4.w) * swv;
    if (WH) {
        ushort4 o; o.x = f2h(rx); o.y = f2h(ry); o.z = f2h(rz); o.w = f2h(rw);
        *(ushort4*)(outh + (size_t)n * D + li * 4) = o;
    }
    if (WF) {
        float4 o; o.x = rx; o.y = ry; o.z = rz; o.w = rw;
        *(float4*)(outf + (size_t)n * D + li * 4) = o;
    }
}

// ---- round 1, item side: i1 = mean(u0) + i0*sw -> fp16 shadow only ----
__global__ void k_agg_r1i(const unsigned short* __restrict__ u0h, const unsigned short* __restrict__ i0h,
                          const float* __restrict__ i_sw,
                          const int* __restrict__ rp_i, const int* __restrict__ col_i,
                          unsigned short* __restrict__ i1h) {
    int g  = (blockIdx.x * blockDim.x + threadIdx.x) >> 4;
    if (g >= NI) return;
    agg_h<false, true>(u0h, i0h, i_sw, rp_i, col_i, nullptr, i1h, g, threadIdx.x & 15, threadIdx.x & 48);
}

// ---- round 1, user side: u1 = mean(i0) + u0*sw -> fp16, IN PLACE over u0h ----
// (separate dispatch from r1i so overwriting u0h is safe: r1i consumed it already)
__global__ void k_agg_r1u(const unsigned short* __restrict__ i0h, const unsigned short* u0h,
                          const float* __restrict__ u_sw,
                          const int* __restrict__ rp_u, const int* __restrict__ col_u,
                          unsigned short* u1h) {
    int g  = (blockIdx.x * blockDim.x + threadIdx.x) >> 4;
    if (g >= NU) return;
    agg_h<false, true>(i0h, u0h, u_sw, rp_u, col_u, nullptr, u1h, g, threadIdx.x & 15, threadIdx.x & 48);
}

// ---- round 2, both sides fused: gather fp16 shadows, write f32 final ----
__global__ void k_agg_r2(const unsigned short* __restrict__ u1h, const unsigned short* __restrict__ i1h,
                         const float* __restrict__ u_sw, const float* __restrict__ i_sw,
                         const int* __restrict__ rp_i, const int* __restrict__ rp_u,
                         const int* __restrict__ col_i, const int* __restrict__ col_u,
                         float* __restrict__ out_i, float* __restrict__ out_u) {
    int g  = (blockIdx.x * blockDim.x + threadIdx.x) >> 4;
    int li = threadIdx.x & 15;
    int lb = threadIdx.x & 48;
    if (g < NI)
        agg_h<true, false>(u1h, i1h, i_sw, rp_i, col_i, out_i, nullptr, g, li, lb);
    else if (g < NI + NU)
        agg_h<true, false>(i1h, u1h, u_sw, rp_u, col_u, out_u, nullptr, g - NI, li, lb);
}

extern "C" void kernel_launch(void* const* d_in, const int* in_sizes, int n_in,
                              void* d_out, int out_size, void* d_ws, size_t ws_size,
                              hipStream_t stream) {
    const float* user_emb = (const float*)d_in[0];
    const float* item_emb = (const float*)d_in[1];
    const float* u_sw     = (const float*)d_in[2];
    const float* i_sw     = (const float*)d_in[3];
    const int*   esrc     = (const int*)d_in[4];   // user endpoint
    const int*   edst     = (const int*)d_in[5];   // item endpoint

    float* out_u = (float*)d_out;          // NU*64 f32
    float* out_i = out_u + NU * D;         // NI*64 f32

    // ---- workspace layout (35.8 MB total — the proven footprint) ----
    // ints (~8.6 MB incl col) | A: u0h 12.8 MB | B: i0h 6.4 MB | C: rec 8 MB
    // aliasing invariants:
    //   u1h == u0h (A): written in-place by r1u AFTER r1i consumed u0h
    //   i1h == rec (C): rec dead after k_local_both
    int* bcnt    = (int*)d_ws;                            // NB_TOT
    int* bbase_i = bcnt + NB_TOT;                         // NBI+1
    int* bbase_u = bbase_i + NBI + 1;                     // NBU+1
    int* gcur_i  = bbase_u + NBU + 1;                     // NBI
    int* gcur_u  = gcur_i + NBI;                          // NBU
    int* rp_i    = gcur_u + NBU;                          // NI+1
    int* rp_u    = rp_i + NI + 1;                         // NU+1
    int* col_i   = rp_u + NU + 1;                         // NE (4 MB)
    int* col_u   = col_i + NE;                            // NE (4 MB)
    uintptr_t pa = ((uintptr_t)(col_u + NE) + 15) & ~(uintptr_t)15;
    unsigned short* u0h = (unsigned short*)pa;            // A: NU*64 fp16 = 12.8 MB
    unsigned short* i0h = u0h + (size_t)NU * D;           // B: NI*64 fp16 = 6.4 MB
    uintptr_t pc = (uintptr_t)(i0h + (size_t)NI * D);
    unsigned int* rec_i = (unsigned int*)pc;              // C: NE
    unsigned int* rec_u = rec_i + NE;                     //    NE
    unsigned short* i1h = (unsigned short*)pc;            // aliases rec (6.4 of 8 MB)
    unsigned short* u1h = u0h;                            // aliases A

    hipMemsetAsync(bcnt, 0, NB_TOT * sizeof(int), stream);

    const int B = 256;

    // ---- CSR build (4 dispatches) + fused input fp16 conversion ----
    k_bhist_cvt<<<1024, B, 0, stream>>>(esrc, edst, bcnt, user_emb, item_emb, u0h, i0h);
    k_bscan_both<<<2, 512, 0, stream>>>(bcnt, bbase_i, gcur_i, bbase_u, gcur_u);
    k_part_both<<<(NE + CHUNK - 1) / CHUNK, B, 0, stream>>>(esrc, edst, gcur_i, gcur_u, rec_i, rec_u);
    k_local_both<<<NB_TOT, B, 0, stream>>>(rec_i, rec_u, bbase_i, bbase_u, rp_i, rp_u, col_i, col_u);

    // ---- aggregation: 16 lanes/node; fp16 gathers (128 B/row, half the f32 traffic) ----
    k_agg_r1i<<<(NI * 16) / B, B, 0, stream>>>(u0h, i0h, i_sw, rp_i, col_i, i1h);
    k_agg_r1u<<<(NU * 16) / B, B, 0, stream>>>(i0h, u0h, u_sw, rp_u, col_u, u1h);
    k_agg_r2<<<((NI + NU) * 16) / B, B, 0, stream>>>(u1h, i1h, u_sw, i_sw,
                                                     rp_i, rp_u, col_i, col_u,
                                                     out_i, out_u);
}